// Round 4
// baseline (267.569 us; speedup 1.0000x reference)
//
#include <hip/hip_runtime.h>

#define IN_SIZE 256
#define OUT_SIZE 64
#define BSHIFT 7         // 128-row buckets
#define BROWS 128
#define BMASK 127
#define CAP 2560         // bucket capacity: mean 2046, sigma 45 -> +11 sigma
#define K1_EDGES 8192    // edges per coarse block (16 per thread, 512 threads)
#define WPAD 264         // 256+8 shorts, breaks LDS bank alias for W tile

typedef __attribute__((ext_vector_type(8))) short short8;   // 8 bf16, 4 VGPRs
typedef __attribute__((ext_vector_type(4))) float floatx4;  // MFMA acc

__device__ inline unsigned short f2bf(float f) {
  unsigned u = __builtin_bit_cast(unsigned, f);
  u += 0x7fff + ((u >> 16) & 1);  // round-to-nearest-even
  return (unsigned short)(u >> 16);
}
__device__ inline float bf2f(unsigned short u) {
  unsigned v = (unsigned)u << 16;
  return __builtin_bit_cast(float, v);
}

// ---------------------------------------------------------------------------
// Shared matmul body: 128 nodes per block, W fp32->bf16 inline into LDS.
__device__ inline void matmul_body(unsigned short* w_lds,  // [64*WPAD]
                                   const float* __restrict__ x,
                                   const float* __restrict__ W,
                                   unsigned short* __restrict__ xwb, int mb,
                                   int n_nodes, int tid) {
  long nbase = (long)mb * 128;
  {
    int r = tid >> 3;  // 0..63
    int q = tid & 7;   // 8 chunks of 32 floats
    const float* src = W + (size_t)r * IN_SIZE + q * 32;
#pragma unroll
    for (int i = 0; i < 4; i++) {
      float4 a = *(const float4*)(src + i * 8);
      float4 b = *(const float4*)(src + i * 8 + 4);
      short8 s;
      s[0] = (short)f2bf(a.x); s[1] = (short)f2bf(a.y);
      s[2] = (short)f2bf(a.z); s[3] = (short)f2bf(a.w);
      s[4] = (short)f2bf(b.x); s[5] = (short)f2bf(b.y);
      s[6] = (short)f2bf(b.z); s[7] = (short)f2bf(b.w);
      *(short8*)(&w_lds[r * WPAD + q * 32 + i * 8]) = s;
    }
  }
  __syncthreads();

  int wave = tid >> 6;
  int lane = tid & 63;
  int quad = lane >> 4;
  int lcol = lane & 15;
  long node = nbase + wave * 16 + lcol;
  long nclamp = (node < (long)n_nodes) ? node : (long)(n_nodes - 1);
  const float* xrow = x + nclamp * IN_SIZE;

  floatx4 acc[4];
#pragma unroll
  for (int t = 0; t < 4; t++) acc[t] = (floatx4){0.f, 0.f, 0.f, 0.f};

#pragma unroll
  for (int kk = 0; kk < 8; kk++) {
    const float* p = xrow + kk * 32 + quad * 8;
    float4 a = *(const float4*)(p);
    float4 bb = *(const float4*)(p + 4);
    short8 bfrag;
    bfrag[0] = (short)f2bf(a.x);  bfrag[1] = (short)f2bf(a.y);
    bfrag[2] = (short)f2bf(a.z);  bfrag[3] = (short)f2bf(a.w);
    bfrag[4] = (short)f2bf(bb.x); bfrag[5] = (short)f2bf(bb.y);
    bfrag[6] = (short)f2bf(bb.z); bfrag[7] = (short)f2bf(bb.w);
#pragma unroll
    for (int t = 0; t < 4; t++) {
      short8 afrag =
          *(const short8*)(&w_lds[(t * 16 + lcol) * WPAD + kk * 32 + quad * 8]);
      acc[t] = __builtin_amdgcn_mfma_f32_16x16x32_bf16(afrag, bfrag, acc[t],
                                                       0, 0, 0);
    }
  }

  if (node < (long)n_nodes) {
#pragma unroll
    for (int t = 0; t < 4; t++) {
      ushort4 sv;
      sv.x = f2bf(acc[t][0]);
      sv.y = f2bf(acc[t][1]);
      sv.z = f2bf(acc[t][2]);
      sv.w = f2bf(acc[t][3]);
      *(ushort4*)(xwb + node * OUT_SIZE + t * 16 + quad * 4) = sv;
    }
  }
}

// ---------------------------------------------------------------------------
// K0: zero the coarse cursors.
__global__ __launch_bounds__(512) void zero_kernel(int* __restrict__ cursor) {
  int i = blockIdx.x * 512 + threadIdx.x;
  if (i < 1024) cursor[i] = 0;
}

// ---------------------------------------------------------------------------
// K1: coarse bucketing (196 blocks) || first half of the matmul. The matmul
// carries NO dinv (deferred to gather), which is what makes it independent
// of the bucketing chain.
struct K1SM {
  union {
    int hist[1024];                 // coarse path (nbuck=782 <= 1024)
    unsigned short w[64 * WPAD];    // matmul path: W tile bf16 (33.8 KB)
  };
};

__global__ __launch_bounds__(512) void k1_kernel(
    const int* __restrict__ row, const int* __restrict__ col,
    int* __restrict__ coarse_cursor, unsigned* __restrict__ pairs,
    const float* __restrict__ x, const float* __restrict__ W,
    unsigned short* __restrict__ xwb, int n_edges, int n_nodes, int nbuck,
    int nb_coarse) {
  __shared__ K1SM sm;
  int tid = threadIdx.x;
  int bid = blockIdx.x;

  if (bid < nb_coarse) {
    // ---- coarse bucketing ----
    sm.hist[tid] = 0;
    sm.hist[tid + 512] = 0;
    __syncthreads();

    int r[16], c[16];
    int ebase = bid * K1_EDGES + tid;
#pragma unroll
    for (int i = 0; i < 16; i++) {
      int e = ebase + i * 512;
      bool ok = e < n_edges;
      r[i] = ok ? row[e] : -1;
      c[i] = ok ? col[e] : -1;
      if (ok && r[i] != c[i]) atomicAdd(&sm.hist[r[i] >> BSHIFT], 1);
    }
    __syncthreads();

    for (int i = tid; i < nbuck; i += 512) {
      int cnt = sm.hist[i];
      if (cnt) sm.hist[i] = atomicAdd(&coarse_cursor[i], cnt);
    }
    __syncthreads();

#pragma unroll
    for (int i = 0; i < 16; i++) {
      if (r[i] >= 0 && r[i] != c[i]) {
        int bin = r[i] >> BSHIFT;
        int slot = atomicAdd(&sm.hist[bin], 1);
        if (slot < CAP)
          pairs[(size_t)bin * CAP + slot] =
              ((unsigned)(r[i] & BMASK) << 17) | (unsigned)c[i];
      }
    }
  } else {
    matmul_body(sm.w, x, W, xwb, bid - nb_coarse, n_nodes, tid);
  }
}

// ---------------------------------------------------------------------------
// K2: fine CSR build (782 blocks) || second half of the matmul. fine depends
// only on K1's coarse output; running it beside the remaining matmul removes
// its serial slot from the critical path.
struct K2SM {
  union {
    struct {
      unsigned lpair[CAP];  // 10 KB
      int hist[BROWS];
      int scn[BROWS];
    } f;
    unsigned short w[64 * WPAD];  // 33.8 KB
  };
};

__global__ __launch_bounds__(512) void k2_kernel(
    const int* __restrict__ coarse_cursor, const unsigned* __restrict__ pairs,
    unsigned* __restrict__ colsp, int* __restrict__ count,
    int* __restrict__ row_start, float* __restrict__ dinv,
    const float* __restrict__ x, const float* __restrict__ W,
    unsigned short* __restrict__ xwb, int n_nodes, int nbuck, int mm_off) {
  __shared__ K2SM sm;
  int tid = threadIdx.x;
  int b = blockIdx.x;

  if (b >= nbuck) {
    matmul_body(sm.w, x, W, xwb, mm_off + (b - nbuck), n_nodes, tid);
    return;
  }

  size_t base = (size_t)b * CAP;
  int n_b = coarse_cursor[b];
  if (n_b > CAP) n_b = CAP;

  if (tid < BROWS) sm.f.hist[tid] = 0;
  __syncthreads();

  for (int i = tid; i < n_b; i += 512) {  // copy + histogram in one pass
    unsigned p = pairs[base + i];
    sm.f.lpair[i] = p;
    atomicAdd(&sm.f.hist[p >> 17], 1);
  }
  __syncthreads();

  if (tid < BROWS) sm.f.scn[tid] = sm.f.hist[tid];
  __syncthreads();
  for (int off = 1; off < BROWS; off <<= 1) {
    int t = (tid >= off && tid < BROWS) ? sm.f.scn[tid - off] : 0;
    __syncthreads();
    if (tid < BROWS) sm.f.scn[tid] += t;
    __syncthreads();
  }

  if (tid < BROWS) {
    int e = (tid > 0) ? sm.f.scn[tid - 1] : 0;
    int r = b * BROWS + tid;
    if (r < n_nodes) {
      int deg = sm.f.hist[tid];
      count[r] = deg;
      row_start[r] = (int)base + e;
      dinv[r] = rsqrtf((float)deg + 1.0f);
    }
    sm.f.hist[tid] = e;  // becomes scatter cursor
  }
  __syncthreads();

  for (int i = tid; i < n_b; i += 512) {
    unsigned p = sm.f.lpair[i];
    int slot = atomicAdd(&sm.f.hist[p >> 17], 1);
    colsp[base + slot] = p & 0x1FFFFu;
  }
}

// ---------------------------------------------------------------------------
// K3: CSR gather, 4 rows/wave, 8 edge-slots x 8 channel-lanes, with a 2-edge
// unroll (idx, idx+8) to double outstanding xwb loads per wave -- round-3
// showed this kernel latency-bound (VALUBusy 30%, BW 22%, conflicts 0).
__global__ __launch_bounds__(256) void gather_kernel(
    const int* __restrict__ row_start, const int* __restrict__ count,
    const unsigned* __restrict__ colsp, const float* __restrict__ dinv,
    const unsigned short* __restrict__ xwb, float* __restrict__ out,
    int n_nodes) {
  int lane = threadIdx.x & 63;
  int wave = threadIdx.x >> 6;
  int sub = lane & 7;   // edge slot
  int cg = lane >> 3;   // channels cg*8 .. cg*8+7
  int rb = (blockIdx.x * 4 + wave) * 4;  // first of 4 rows
  if (rb >= n_nodes) return;

  int start[4], cnt[4];
  int maxc = 0;
#pragma unroll
  for (int i = 0; i < 4; i++) {
    int r = rb + i;
    bool ok = r < n_nodes;
    start[i] = ok ? row_start[r] : 0;
    cnt[i] = ok ? count[r] : 0;
    maxc = max(maxc, cnt[i]);
  }

  float acc[4][8];
#pragma unroll
  for (int i = 0; i < 4; i++)
#pragma unroll
    for (int k = 0; k < 8; k++) acc[i][k] = 0.f;

  if (sub == 0) {  // self-loop terms: dinv[r]*xw[r]
#pragma unroll
    for (int i = 0; i < 4; i++) {
      int r = rb + i;
      if (r < n_nodes) {
        float dv = dinv[r];
        short8 v = *(const short8*)(xwb + (size_t)r * OUT_SIZE + cg * 8);
#pragma unroll
        for (int k = 0; k < 8; k++) acc[i][k] = dv * bf2f((unsigned short)v[k]);
      }
    }
  }

  for (int j = 0; j < maxc; j += 16) {
    int c0[4], c1[4];
    float m0[4], m1[4];
    int idx0 = j + sub;
    int idx1 = idx0 + 8;
#pragma unroll
    for (int i = 0; i < 4; i++) {
      bool a0 = idx0 < cnt[i];
      bool a1 = idx1 < cnt[i];
      c0[i] = a0 ? (int)colsp[start[i] + idx0] : rb;  // dummy -> hot line
      c1[i] = a1 ? (int)colsp[start[i] + idx1] : rb;
      m0[i] = a0 ? dinv[c0[i]] : 0.0f;
      m1[i] = a1 ? dinv[c1[i]] : 0.0f;
    }
    short8 v0[4], v1[4];
#pragma unroll
    for (int i = 0; i < 4; i++) {
      v0[i] = *(const short8*)(xwb + (size_t)c0[i] * OUT_SIZE + cg * 8);
      v1[i] = *(const short8*)(xwb + (size_t)c1[i] * OUT_SIZE + cg * 8);
    }
#pragma unroll
    for (int i = 0; i < 4; i++)
#pragma unroll
      for (int k = 0; k < 8; k++)
        acc[i][k] += m0[i] * bf2f((unsigned short)v0[i][k]);
#pragma unroll
    for (int i = 0; i < 4; i++)
#pragma unroll
      for (int k = 0; k < 8; k++)
        acc[i][k] += m1[i] * bf2f((unsigned short)v1[i][k]);
  }

#pragma unroll
  for (int i = 0; i < 4; i++)
#pragma unroll
    for (int k = 0; k < 8; k++) {
      acc[i][k] += __shfl_xor(acc[i][k], 1);
      acc[i][k] += __shfl_xor(acc[i][k], 2);
      acc[i][k] += __shfl_xor(acc[i][k], 4);
    }

  if (sub == 0) {
#pragma unroll
    for (int i = 0; i < 4; i++) {
      int r = rb + i;
      if (r < n_nodes) {
        float dr = dinv[r];
        float* dst = out + (size_t)r * OUT_SIZE + cg * 8;
        *(float4*)(dst) =
            make_float4(dr * acc[i][0], dr * acc[i][1], dr * acc[i][2],
                        dr * acc[i][3]);
        *(float4*)(dst + 4) =
            make_float4(dr * acc[i][4], dr * acc[i][5], dr * acc[i][6],
                        dr * acc[i][7]);
      }
    }
  }
}

// ---------------------------------------------------------------------------
extern "C" void kernel_launch(void* const* d_in, const int* in_sizes, int n_in,
                              void* d_out, int out_size, void* d_ws,
                              size_t ws_size, hipStream_t stream) {
  const int* edge_index = (const int*)d_in[0];
  const float* x = (const float*)d_in[1];
  const float* W = (const float*)d_in[3];

  int n_edges = in_sizes[0] / 2;
  int n_nodes = in_sizes[1] / IN_SIZE;
  const int* row = edge_index;
  const int* col = edge_index + n_edges;
  float* out = (float*)d_out;

  int nbuck = (n_nodes + BROWS - 1) >> BSHIFT;          // 782
  int nb_coarse = (n_edges + K1_EDGES - 1) / K1_EDGES;  // 196
  int nb_mm = (n_nodes + 127) / 128;                    // 782
  int nmm1 = nb_mm / 2;                                 // matmul blocks in K1

  // Workspace: count[N] | row_start[N] | dinv[N] | coarse_cursor(4KB) |
  //            pairs[nbuck*CAP u32] | colsp[nbuck*CAP u32] | xwb[N*64 bf16]
  char* ws = (char*)d_ws;
  size_t nb4 = ((size_t)n_nodes * 4 + 15) & ~(size_t)15;
  int* count = (int*)ws;
  int* row_start = (int*)(ws + nb4);
  float* dinv = (float*)(ws + 2 * nb4);
  int* coarse_cursor = (int*)(ws + 3 * nb4);
  size_t pairsB = (size_t)nbuck * CAP * 4;  // 8,007,680 B
  unsigned* pairs = (unsigned*)(ws + 3 * nb4 + 4096);
  unsigned* colsp = (unsigned*)(ws + 3 * nb4 + 4096 + pairsB);
  unsigned short* xwb =
      (unsigned short*)(ws + 3 * nb4 + 4096 + 2 * pairsB);

  zero_kernel<<<2, 512, 0, stream>>>(coarse_cursor);
  k1_kernel<<<nb_coarse + nmm1, 512, 0, stream>>>(
      row, col, coarse_cursor, pairs, x, W, xwb, n_edges, n_nodes, nbuck,
      nb_coarse);
  k2_kernel<<<nbuck + (nb_mm - nmm1), 512, 0, stream>>>(
      coarse_cursor, pairs, colsp, count, row_start, dinv, x, W, xwb,
      n_nodes, nbuck, nmm1);
  gather_kernel<<<(n_nodes + 15) / 16, 256, 0, stream>>>(
      row_start, count, colsp, dinv, xwb, out, n_nodes);
}

// Round 6
// 256.653 us; speedup vs baseline: 1.0425x; 1.0425x over previous
//
#include <hip/hip_runtime.h>

#define IN_SIZE 256
#define OUT_SIZE 64
#define BSHIFT 7         // 128-row buckets
#define BROWS 128
#define BMASK 127
#define CAP 2560         // bucket capacity: mean 2046, sigma 45 -> +11 sigma
#define K1_EDGES 8192    // edges per coarse block (16 per thread, 512 threads)
#define WPAD 264         // 256+8 shorts, breaks LDS bank alias for W tile

typedef __attribute__((ext_vector_type(8))) short short8;   // 8 bf16, 4 VGPRs
typedef __attribute__((ext_vector_type(4))) float floatx4;  // MFMA acc

__device__ inline unsigned short f2bf(float f) {
  unsigned u = __builtin_bit_cast(unsigned, f);
  u += 0x7fff + ((u >> 16) & 1);  // round-to-nearest-even
  return (unsigned short)(u >> 16);
}
__device__ inline float bf2f(unsigned short u) {
  unsigned v = (unsigned)u << 16;
  return __builtin_bit_cast(float, v);
}

// ---------------------------------------------------------------------------
// K0: zero the coarse cursors.
__global__ __launch_bounds__(512) void zero_kernel(int* __restrict__ cursor) {
  int i = blockIdx.x * 512 + threadIdx.x;
  if (i < 1024) cursor[i] = 0;
}

// ---------------------------------------------------------------------------
// K1: heterogeneous grid (round-3 config -- the round-4 two-kernel matmul
// split cost ~7us and was reverted). Blocks [0, nb_coarse): coarse bucketing
// by row>>7. Blocks [nb_coarse, ...): xwb = bf16(x @ W.T) with NO dinv
// (deferred to gather) -- keeps matmul independent of the bucketing chain.
struct K1SM {
  union {
    int hist[1024];                 // coarse path (nbuck=782 <= 1024)
    unsigned short w[64 * WPAD];    // matmul path: W tile bf16 (33.8 KB)
  };
};

__global__ __launch_bounds__(512) void fused1_kernel(
    const int* __restrict__ row, const int* __restrict__ col,
    int* __restrict__ coarse_cursor, unsigned* __restrict__ pairs,
    const float* __restrict__ x, const float* __restrict__ W,
    unsigned short* __restrict__ xwb, int n_edges, int n_nodes, int nbuck,
    int nb_coarse) {
  __shared__ K1SM sm;
  int tid = threadIdx.x;
  int bid = blockIdx.x;

  if (bid < nb_coarse) {
    // ---- coarse bucketing ----
    sm.hist[tid] = 0;
    sm.hist[tid + 512] = 0;
    __syncthreads();

    int r[16], c[16];
    int ebase = bid * K1_EDGES + tid;
#pragma unroll
    for (int i = 0; i < 16; i++) {
      int e = ebase + i * 512;
      bool ok = e < n_edges;
      r[i] = ok ? row[e] : -1;
      c[i] = ok ? col[e] : -1;
      if (ok && r[i] != c[i]) atomicAdd(&sm.hist[r[i] >> BSHIFT], 1);
    }
    __syncthreads();

    for (int i = tid; i < nbuck; i += 512) {
      int cnt = sm.hist[i];
      if (cnt) sm.hist[i] = atomicAdd(&coarse_cursor[i], cnt);
    }
    __syncthreads();

#pragma unroll
    for (int i = 0; i < 16; i++) {
      if (r[i] >= 0 && r[i] != c[i]) {
        int bin = r[i] >> BSHIFT;
        int slot = atomicAdd(&sm.hist[bin], 1);
        if (slot < CAP)
          pairs[(size_t)bin * CAP + slot] =
              ((unsigned)(r[i] & BMASK) << 17) | (unsigned)c[i];
      }
    }
  } else {
    // ---- matmul: 128 nodes per block, W converted fp32->bf16 inline ----
    int mb = bid - nb_coarse;
    long nbase = (long)mb * 128;
    {
      int r = tid >> 3;  // 0..63
      int q = tid & 7;   // 8 chunks of 32 floats
      const float* src = W + (size_t)r * IN_SIZE + q * 32;
#pragma unroll
      for (int i = 0; i < 4; i++) {
        float4 a = *(const float4*)(src + i * 8);
        float4 b = *(const float4*)(src + i * 8 + 4);
        short8 s;
        s[0] = (short)f2bf(a.x); s[1] = (short)f2bf(a.y);
        s[2] = (short)f2bf(a.z); s[3] = (short)f2bf(a.w);
        s[4] = (short)f2bf(b.x); s[5] = (short)f2bf(b.y);
        s[6] = (short)f2bf(b.z); s[7] = (short)f2bf(b.w);
        *(short8*)(&sm.w[r * WPAD + q * 32 + i * 8]) = s;
      }
    }
    __syncthreads();

    int wave = tid >> 6;
    int lane = tid & 63;
    int quad = lane >> 4;
    int lcol = lane & 15;
    long node = nbase + wave * 16 + lcol;
    long nclamp = (node < (long)n_nodes) ? node : (long)(n_nodes - 1);
    const float* xrow = x + nclamp * IN_SIZE;

    floatx4 acc[4];
#pragma unroll
    for (int t = 0; t < 4; t++) acc[t] = (floatx4){0.f, 0.f, 0.f, 0.f};

#pragma unroll
    for (int kk = 0; kk < 8; kk++) {
      const float* p = xrow + kk * 32 + quad * 8;
      float4 a = *(const float4*)(p);
      float4 bb = *(const float4*)(p + 4);
      short8 bfrag;
      bfrag[0] = (short)f2bf(a.x);  bfrag[1] = (short)f2bf(a.y);
      bfrag[2] = (short)f2bf(a.z);  bfrag[3] = (short)f2bf(a.w);
      bfrag[4] = (short)f2bf(bb.x); bfrag[5] = (short)f2bf(bb.y);
      bfrag[6] = (short)f2bf(bb.z); bfrag[7] = (short)f2bf(bb.w);
#pragma unroll
      for (int t = 0; t < 4; t++) {
        short8 afrag =
            *(const short8*)(&sm.w[(t * 16 + lcol) * WPAD + kk * 32 + quad * 8]);
        acc[t] = __builtin_amdgcn_mfma_f32_16x16x32_bf16(afrag, bfrag, acc[t],
                                                         0, 0, 0);
      }
    }

    if (node < (long)n_nodes) {
#pragma unroll
      for (int t = 0; t < 4; t++) {
        ushort4 sv;
        sv.x = f2bf(acc[t][0]);
        sv.y = f2bf(acc[t][1]);
        sv.z = f2bf(acc[t][2]);
        sv.w = f2bf(acc[t][3]);
        *(ushort4*)(xwb + node * OUT_SIZE + t * 16 + quad * 4) = sv;
      }
    }
  }
}

// ---------------------------------------------------------------------------
// K2: fine CSR build, single-pass (round-0/3 structure verbatim).
__global__ __launch_bounds__(256) void fine_kernel(
    const int* __restrict__ coarse_cursor, const unsigned* __restrict__ pairs,
    unsigned* __restrict__ colsp, int* __restrict__ count,
    int* __restrict__ row_start, float* __restrict__ dinv, int n_nodes) {
  __shared__ unsigned lpair[CAP];  // 10 KB
  __shared__ int hist[BROWS];
  __shared__ int scn[BROWS];
  int tid = threadIdx.x;
  int b = blockIdx.x;
  size_t base = (size_t)b * CAP;
  int n_b = coarse_cursor[b];
  if (n_b > CAP) n_b = CAP;

  if (tid < BROWS) hist[tid] = 0;
  __syncthreads();

  for (int i = tid; i < n_b; i += 256) {  // copy + histogram in one pass
    unsigned p = pairs[base + i];
    lpair[i] = p;
    atomicAdd(&hist[p >> 17], 1);
  }
  __syncthreads();

  if (tid < BROWS) scn[tid] = hist[tid];
  __syncthreads();
  for (int off = 1; off < BROWS; off <<= 1) {
    int t = (tid >= off && tid < BROWS) ? scn[tid - off] : 0;
    __syncthreads();
    if (tid < BROWS) scn[tid] += t;
    __syncthreads();
  }

  if (tid < BROWS) {
    int e = (tid > 0) ? scn[tid - 1] : 0;
    int r = b * BROWS + tid;
    if (r < n_nodes) {
      int deg = hist[tid];
      count[r] = deg;
      row_start[r] = (int)base + e;
      dinv[r] = rsqrtf((float)deg + 1.0f);
    }
    hist[tid] = e;  // becomes scatter cursor
  }
  __syncthreads();

  for (int i = tid; i < n_b; i += 256) {
    unsigned p = lpair[i];
    int slot = atomicAdd(&hist[p >> 17], 1);
    colsp[base + slot] = p & 0x1FFFFu;
  }
}

// ---------------------------------------------------------------------------
// K3: CSR gather, 4 rows/wave (round-3 shape: 48-VGPR class, occupancy 45%)
// + software-pipelined colsp/dinv prefetch. Round-3 showed the loop is
// latency-bound on the serial chain colsp->dinv->xwb (~800cy); issuing the
// NEXT iteration's colsp+dinv while the current xwb loads are in flight cuts
// steady-state per-iter latency to max(L_xwb, L_colsp+L_dinv). Round-4's
// 2-edge unroll (64 VGPR, occ 36%) is reverted -- prefetch adds only 8 VGPRs.
__global__ __launch_bounds__(256) void gather_kernel(
    const int* __restrict__ row_start, const int* __restrict__ count,
    const unsigned* __restrict__ colsp, const float* __restrict__ dinv,
    const unsigned short* __restrict__ xwb, float* __restrict__ out,
    int n_nodes) {
  int lane = threadIdx.x & 63;
  int wave = threadIdx.x >> 6;
  int sub = lane & 7;   // edge slot
  int cg = lane >> 3;   // channels cg*8 .. cg*8+7
  int rb = (blockIdx.x * 4 + wave) * 4;  // first of 4 rows
  if (rb >= n_nodes) return;

  int start[4], cnt[4];
  int maxc = 0;
#pragma unroll
  for (int i = 0; i < 4; i++) {
    int r = rb + i;
    bool ok = r < n_nodes;
    start[i] = ok ? row_start[r] : 0;
    cnt[i] = ok ? count[r] : 0;
    maxc = max(maxc, cnt[i]);
  }

  float acc[4][8];
#pragma unroll
  for (int i = 0; i < 4; i++)
#pragma unroll
    for (int k = 0; k < 8; k++) acc[i][k] = 0.f;

  if (sub == 0) {  // self-loop terms: dinv[r]*xw[r]
#pragma unroll
    for (int i = 0; i < 4; i++) {
      int r = rb + i;
      if (r < n_nodes) {
        float dv = dinv[r];
        short8 v = *(const short8*)(xwb + (size_t)r * OUT_SIZE + cg * 8);
#pragma unroll
        for (int k = 0; k < 8; k++) acc[i][k] = dv * bf2f((unsigned short)v[k]);
      }
    }
  }

  // prologue: prefetch c/m for j=0
  int cN[4];
  float mN[4];
#pragma unroll
  for (int i = 0; i < 4; i++) {
    bool act = sub < cnt[i];
    cN[i] = act ? (int)colsp[start[i] + sub] : rb;  // dummy -> hot line
    mN[i] = act ? dinv[cN[i]] : 0.0f;
  }

  for (int j = 0; j < maxc; j += 8) {
    int c[4];
    float m[4];
#pragma unroll
    for (int i = 0; i < 4; i++) {
      c[i] = cN[i];
      m[i] = mN[i];
    }
    // issue the xwb row loads for the current iteration FIRST...
    short8 v[4];
#pragma unroll
    for (int i = 0; i < 4; i++)
      v[i] = *(const short8*)(xwb + (size_t)c[i] * OUT_SIZE + cg * 8);
    // ...then the next iteration's colsp+dinv, so they are in flight while
    // the FMAs below wait on v (in-order vmcnt leaves them outstanding).
    int jn = j + 8;
    if (jn < maxc) {
      int idx = jn + sub;
#pragma unroll
      for (int i = 0; i < 4; i++) {
        bool act = idx < cnt[i];
        cN[i] = act ? (int)colsp[start[i] + idx] : rb;
        mN[i] = act ? dinv[cN[i]] : 0.0f;
      }
    }
#pragma unroll
    for (int i = 0; i < 4; i++)
#pragma unroll
      for (int k = 0; k < 8; k++)
        acc[i][k] += m[i] * bf2f((unsigned short)v[i][k]);
  }

#pragma unroll
  for (int i = 0; i < 4; i++)
#pragma unroll
    for (int k = 0; k < 8; k++) {
      acc[i][k] += __shfl_xor(acc[i][k], 1);
      acc[i][k] += __shfl_xor(acc[i][k], 2);
      acc[i][k] += __shfl_xor(acc[i][k], 4);
    }

  if (sub == 0) {
#pragma unroll
    for (int i = 0; i < 4; i++) {
      int r = rb + i;
      if (r < n_nodes) {
        float dr = dinv[r];
        float* dst = out + (size_t)r * OUT_SIZE + cg * 8;
        *(float4*)(dst) =
            make_float4(dr * acc[i][0], dr * acc[i][1], dr * acc[i][2],
                        dr * acc[i][3]);
        *(float4*)(dst + 4) =
            make_float4(dr * acc[i][4], dr * acc[i][5], dr * acc[i][6],
                        dr * acc[i][7]);
      }
    }
  }
}

// ---------------------------------------------------------------------------
extern "C" void kernel_launch(void* const* d_in, const int* in_sizes, int n_in,
                              void* d_out, int out_size, void* d_ws,
                              size_t ws_size, hipStream_t stream) {
  const int* edge_index = (const int*)d_in[0];
  const float* x = (const float*)d_in[1];
  const float* W = (const float*)d_in[3];

  int n_edges = in_sizes[0] / 2;
  int n_nodes = in_sizes[1] / IN_SIZE;
  const int* row = edge_index;
  const int* col = edge_index + n_edges;
  float* out = (float*)d_out;

  int nbuck = (n_nodes + BROWS - 1) >> BSHIFT;          // 782
  int nb_coarse = (n_edges + K1_EDGES - 1) / K1_EDGES;  // 196
  int nb_mm = (n_nodes + 127) / 128;                    // 782

  // Workspace: count[N] | row_start[N] | dinv[N] | coarse_cursor(4KB) |
  //            pairs[nbuck*CAP u32] | colsp[nbuck*CAP u32] | xwb[N*64 bf16]
  char* ws = (char*)d_ws;
  size_t nb4 = ((size_t)n_nodes * 4 + 15) & ~(size_t)15;
  int* count = (int*)ws;
  int* row_start = (int*)(ws + nb4);
  float* dinv = (float*)(ws + 2 * nb4);
  int* coarse_cursor = (int*)(ws + 3 * nb4);
  size_t pairsB = (size_t)nbuck * CAP * 4;  // 8,007,680 B
  unsigned* pairs = (unsigned*)(ws + 3 * nb4 + 4096);
  unsigned* colsp = (unsigned*)(ws + 3 * nb4 + 4096 + pairsB);
  unsigned short* xwb =
      (unsigned short*)(ws + 3 * nb4 + 4096 + 2 * pairsB);

  zero_kernel<<<2, 512, 0, stream>>>(coarse_cursor);
  fused1_kernel<<<nb_coarse + nb_mm, 512, 0, stream>>>(
      row, col, coarse_cursor, pairs, x, W, xwb, n_edges, n_nodes, nbuck,
      nb_coarse);
  fine_kernel<<<nbuck, 256, 0, stream>>>(coarse_cursor, pairs, colsp, count,
                                         row_start, dinv, n_nodes);
  gather_kernel<<<(n_nodes + 15) / 16, 256, 0, stream>>>(
      row_start, count, colsp, dinv, xwb, out, n_nodes);
}